// Round 2
// baseline (702.114 us; speedup 1.0000x reference)
//
#include <hip/hip_runtime.h>

#define BATCH 2048
#define IN_SZ 40960
#define IN4   (IN_SZ / 4)
#define HID   256
#define LCAP  64   // per-row per-perspective index capacity (ACTIVE=30 max)

// ---------------------------------------------------------------------------
// Transpose ft_w [HID][IN_SZ] -> ftT [IN_SZ][HID] so per-feature gathers are
// contiguous 1KB rows. 32x32 LDS tile, padded to kill bank conflicts.
// ---------------------------------------------------------------------------
__global__ __launch_bounds__(256) void ft_transpose(const float* __restrict__ ftw,
                                                    float* __restrict__ ftT) {
    __shared__ float tile[32][33];
    const int tx = threadIdx.x;   // 0..31
    const int ty = threadIdx.y;   // 0..7
    const int bx = blockIdx.x;    // IN_SZ/32 = 1280
    const int by = blockIdx.y;    // HID/32  = 8

    const int col = bx * 32 + tx;               // IN index (coalesced read)
#pragma unroll
    for (int j = 0; j < 32; j += 8) {
        const int row = by * 32 + ty + j;       // HID index
        tile[ty + j][tx] = ftw[(size_t)row * IN_SZ + col];
    }
    __syncthreads();

    const int ocol = by * 32 + tx;              // HID index (coalesced write)
#pragma unroll
    for (int j = 0; j < 32; j += 8) {
        const int orow = bx * 32 + ty + j;      // IN index
        ftT[(size_t)orow * HID + ocol] = tile[tx][ty + j];
    }
}

// ---------------------------------------------------------------------------
// Pure streaming extraction: grid-stride float4 scan of one perspective
// (blockIdx.y selects white/black). Nonzero components (values are exactly
// 0.0/1.0, so a component-sum test is exact) push feature indices into
// per-(row,perspective) compact lists via global atomics.
// ---------------------------------------------------------------------------
__global__ __launch_bounds__(256) void extract(const float* __restrict__ wo,
                                               const float* __restrict__ bo,
                                               int* __restrict__ cnt,    // [BATCH][2]
                                               int* __restrict__ lists)  // [BATCH][2][LCAP]
{
    const int persp = blockIdx.y;
    const float4* __restrict__ src = (const float4*)(persp ? bo : wo);
    const int stride = gridDim.x * blockDim.x;
    for (int i = blockIdx.x * blockDim.x + threadIdx.x; i < BATCH * IN4; i += stride) {
        const float4 v = src[i];
        if (((v.x + v.y) + (v.z + v.w)) != 0.f) {   // exact: components are 0.0 or 1.0
            const int row = i / IN4;
            const int f0  = (i - row * IN4) * 4;
            int* c = cnt + row * 2 + persp;
            int* l = lists + (row * 2 + persp) * LCAP;
            if (v.x != 0.f) l[atomicAdd(c, 1)] = f0;
            if (v.y != 0.f) l[atomicAdd(c, 1)] = f0 + 1;
            if (v.z != 0.f) l[atomicAdd(c, 1)] = f0 + 2;
            if (v.w != 0.f) l[atomicAdd(c, 1)] = f0 + 3;
        }
    }
}

// ---------------------------------------------------------------------------
// Per-row feature-transformer + MLP. One block (256 thr) per batch row.
// Gathers are coalesced 1KB rows of the L3-resident ftT table.
// ---------------------------------------------------------------------------
__global__ __launch_bounds__(256) void ft_mlp(
    const int* __restrict__ cnt, const int* __restrict__ lists,
    const float* __restrict__ stm,
    const float* __restrict__ ftT, const float* __restrict__ ftb,
    const float* __restrict__ l1w, const float* __restrict__ l1b,
    const float* __restrict__ l2w, const float* __restrict__ l2b,
    const float* __restrict__ l3w, const float* __restrict__ l3b,
    float* __restrict__ out) {
    __shared__ int   sidx[2 * LCAP];
    __shared__ float hidden[2 * HID];
    __shared__ float x1[32], x2[32];

    const int b = blockIdx.x;
    const int t = threadIdx.x;

    if (t < 2 * LCAP) sidx[t] = lists[b * 2 * LCAP + t];
    __syncthreads();

    const int cw = cnt[b * 2 + 0];
    const int cb = cnt[b * 2 + 1];

    // ---- feature transformer: h = t (0..255) ----
    float accw = ftb[t];
    float accb = accw;
    for (int j = 0; j < cw; ++j) accw += ftT[(size_t)sidx[j] * HID + t];
    for (int j = 0; j < cb; ++j) accb += ftT[(size_t)sidx[LCAP + j] * HID + t];
    accw = fminf(fmaxf(accw, 0.f), 1.f);
    accb = fminf(fmaxf(accb, 0.f), 1.f);

    // ---- stm-ordered concat ----
    const bool s = (stm[b] != 0.f);
    hidden[t]       = s ? accw : accb;
    hidden[HID + t] = s ? accb : accw;
    __syncthreads();

    // ---- l1 (512 -> 32): 8 lanes per output, shuffle reduce ----
    {
        const int o = t >> 3;              // 0..31
        const int part = t & 7;            // 0..7
        const float* w1 = l1w + o * (2 * HID);
        float sum = 0.f;
#pragma unroll 8
        for (int i = part; i < 2 * HID; i += 8)
            sum += hidden[i] * w1[i];
        sum += __shfl_xor(sum, 1);
        sum += __shfl_xor(sum, 2);
        sum += __shfl_xor(sum, 4);
        if (part == 0) x1[o] = fminf(fmaxf(sum + l1b[o], 0.f), 1.f);
    }
    __syncthreads();

    // ---- l2 (32 -> 32) ----
    if (t < 32) {
        const float* w2 = l2w + t * 32;
        float sum = l2b[t];
#pragma unroll
        for (int i = 0; i < 32; ++i) sum += x1[i] * w2[i];
        x2[t] = fminf(fmaxf(sum, 0.f), 1.f);
    }
    __syncthreads();

    // ---- l3 (32 -> 1) ----
    if (t == 0) {
        float sum = l3b[0];
#pragma unroll
        for (int i = 0; i < 32; ++i) sum += x2[i] * l3w[i];
        out[b] = sum;
    }
}

// ---------------------------------------------------------------------------
// Fallback (ws too small): fully fused, untransposed gather. Correct, slower.
// ---------------------------------------------------------------------------
__global__ __launch_bounds__(256) void nnue_fused_fallback(
    const float* __restrict__ wo, const float* __restrict__ bo,
    const float* __restrict__ stm,
    const float* __restrict__ ftw, const float* __restrict__ ftb,
    const float* __restrict__ l1w, const float* __restrict__ l1b,
    const float* __restrict__ l2w, const float* __restrict__ l2b,
    const float* __restrict__ l3w, const float* __restrict__ l3b,
    float* __restrict__ out) {
    __shared__ int   idxw[LCAP], idxb[LCAP];
    __shared__ int   cntw, cntb;
    __shared__ float hidden[2 * HID];
    __shared__ float x1[32], x2[32];

    const int b = blockIdx.x;
    const int t = threadIdx.x;
    if (t == 0) { cntw = 0; cntb = 0; }
    __syncthreads();

    const float4* wrow = (const float4*)(wo + (size_t)b * IN_SZ);
    const float4* brow = (const float4*)(bo + (size_t)b * IN_SZ);
    for (int i = t; i < IN4; i += 256) {
        float4 v = wrow[i];
        float4 u = brow[i];
        if (((v.x + v.y) + (v.z + v.w)) != 0.f) {
            if (v.x != 0.f) idxw[atomicAdd(&cntw, 1)] = 4 * i;
            if (v.y != 0.f) idxw[atomicAdd(&cntw, 1)] = 4 * i + 1;
            if (v.z != 0.f) idxw[atomicAdd(&cntw, 1)] = 4 * i + 2;
            if (v.w != 0.f) idxw[atomicAdd(&cntw, 1)] = 4 * i + 3;
        }
        if (((u.x + u.y) + (u.z + u.w)) != 0.f) {
            if (u.x != 0.f) idxb[atomicAdd(&cntb, 1)] = 4 * i;
            if (u.y != 0.f) idxb[atomicAdd(&cntb, 1)] = 4 * i + 1;
            if (u.z != 0.f) idxb[atomicAdd(&cntb, 1)] = 4 * i + 2;
            if (u.w != 0.f) idxb[atomicAdd(&cntb, 1)] = 4 * i + 3;
        }
    }
    __syncthreads();

    float accw = ftb[t], accb = accw;
    for (int j = 0; j < cntw; ++j) accw += ftw[(size_t)t * IN_SZ + idxw[j]];
    for (int j = 0; j < cntb; ++j) accb += ftw[(size_t)t * IN_SZ + idxb[j]];
    accw = fminf(fmaxf(accw, 0.f), 1.f);
    accb = fminf(fmaxf(accb, 0.f), 1.f);

    const bool s = (stm[b] != 0.f);
    hidden[t]       = s ? accw : accb;
    hidden[HID + t] = s ? accb : accw;
    __syncthreads();

    {
        const int o = t >> 3, part = t & 7;
        const float* w1 = l1w + o * (2 * HID);
        float sum = 0.f;
        for (int i = part; i < 2 * HID; i += 8) sum += hidden[i] * w1[i];
        sum += __shfl_xor(sum, 1);
        sum += __shfl_xor(sum, 2);
        sum += __shfl_xor(sum, 4);
        if (part == 0) x1[o] = fminf(fmaxf(sum + l1b[o], 0.f), 1.f);
    }
    __syncthreads();
    if (t < 32) {
        float sum = l2b[t];
        for (int i = 0; i < 32; ++i) sum += x1[i] * l2w[t * 32 + i];
        x2[t] = fminf(fmaxf(sum, 0.f), 1.f);
    }
    __syncthreads();
    if (t == 0) {
        float sum = l3b[0];
        for (int i = 0; i < 32; ++i) sum += x2[i] * l3w[i];
        out[b] = sum;
    }
}

extern "C" void kernel_launch(void* const* d_in, const int* in_sizes, int n_in,
                              void* d_out, int out_size, void* d_ws, size_t ws_size,
                              hipStream_t stream) {
    const float* wo  = (const float*)d_in[0];
    const float* bo  = (const float*)d_in[1];
    const float* stm = (const float*)d_in[2];
    const float* ftw = (const float*)d_in[3];
    const float* ftb = (const float*)d_in[4];
    const float* l1w = (const float*)d_in[5];
    const float* l1b = (const float*)d_in[6];
    const float* l2w = (const float*)d_in[7];
    const float* l2b = (const float*)d_in[8];
    const float* l3w = (const float*)d_in[9];
    const float* l3b = (const float*)d_in[10];
    float* out = (float*)d_out;

    // workspace layout
    const size_t ftT_bytes  = (size_t)IN_SZ * HID * sizeof(float);          // 41.9 MB
    const size_t cnt_off    = 44 * 1024 * 1024;                             // aligned past ftT
    const size_t cnt_bytes  = (size_t)BATCH * 2 * sizeof(int);              // 16 KB
    const size_t list_off   = cnt_off + cnt_bytes;
    const size_t list_bytes = (size_t)BATCH * 2 * LCAP * sizeof(int);       // 1 MB
    const size_t need       = list_off + list_bytes;

    if (ws_size >= need && ftT_bytes <= cnt_off) {
        float* ftT  = (float*)d_ws;
        int* cnt    = (int*)((char*)d_ws + cnt_off);
        int* lists  = (int*)((char*)d_ws + list_off);

        hipMemsetAsync(cnt, 0, cnt_bytes, stream);
        ft_transpose<<<dim3(IN_SZ / 32, HID / 32), dim3(32, 8), 0, stream>>>(ftw, ftT);
        extract<<<dim3(1024, 2), 256, 0, stream>>>(wo, bo, cnt, lists);
        ft_mlp<<<BATCH, 256, 0, stream>>>(cnt, lists, stm, ftT, ftb,
                                          l1w, l1b, l2w, l2b, l3w, l3b, out);
    } else {
        nnue_fused_fallback<<<BATCH, 256, 0, stream>>>(wo, bo, stm, ftw, ftb,
                                                       l1w, l1b, l2w, l2b, l3w, l3b, out);
    }
}